// Round 4
// baseline (773.220 us; speedup 1.0000x reference)
//
#include <hip/hip_runtime.h>

#define BB 256
#define TT 2048
#define KK 64
#define CHUNK 64
#define NCHUNK (TT / CHUNK)   // 32
#define NEG_INF_F (-10000.0f)

// DPP quad_perm helpers (free VALU cross-lane within quads)
#define DPP_XOR1 0xB1   // quad_perm [1,0,3,2]
#define DPP_XOR2 0x4E   // quad_perm [2,3,0,1]

template <int CTRL>
__device__ __forceinline__ float dpp_f(float x) {
    return __int_as_float(__builtin_amdgcn_update_dpp(
        0, __float_as_int(x), CTRL, 0xF, 0xF, true));
}
template <int CTRL>
__device__ __forceinline__ int dpp_i(int x) {
    return __builtin_amdgcn_update_dpp(0, x, CTRL, 0xF, 0xF, true);
}

// LDS-only barrier: don't drain vmcnt (feat prefetch / bp stores stay in flight)
__device__ __forceinline__ void lds_barrier() {
    asm volatile("s_waitcnt lgkmcnt(0)\n\ts_barrier" ::: "memory");
}

__global__ __launch_bounds__(256)
void viterbi_fwd_bt(const float* __restrict__ feats,
                    const float* __restrict__ trans,
                    const int* __restrict__ start_tag_p,
                    const int* __restrict__ stop_tag_p,
                    float* __restrict__ out,
                    unsigned char* __restrict__ bp_ws)
{
    const int b    = blockIdx.x;
    const int tid  = threadIdx.x;
    const int lane = tid & 63;
    const int w    = __builtin_amdgcn_readfirstlane(tid >> 6);  // wave 0..3
    const int g    = lane >> 2;        // row group within wave (16 rows/wave)
    const int j    = lane & 3;         // p-chunk within row (4 chunks of 16)
    const int n    = w * 16 + g;       // owned output row
    const int pbase = j * 16;

    const int start_tag = *start_tag_p;
    const int stop_tag  = *stop_tag_p;

    __shared__ float fv_lds[2][KK];    // double-buffered Viterbi variables
    __shared__ int   cmap[NCHUNK][KK]; // composed backpointer maps per chunk
    __shared__ int   be_lds[NCHUNK];
    __shared__ int   bl_lds;

    const float* fb = feats + (size_t)b * TT * KK;
    unsigned char* bpb = bp_ws + (size_t)b * TT * KK;

    // per-lane transition fragment: trans[n][pbase .. pbase+15]
    const float4* trp = (const float4*)&trans[n * KK + pbase];
    const float4 tA = trp[0], tB = trp[1], tC = trp[2], tD = trp[3];
    const float tstop = trans[stop_tag * KK + lane];

    if (tid < KK) fv_lds[0][tid] = (tid == start_tag) ? 0.0f : NEG_INF_F;
    __syncthreads();

    // feat prefetch ring (depth 4); 4-lane broadcast per row
    float r0 = fb[0 * KK + n];
    float r1 = fb[1 * KK + n];
    float r2 = fb[2 * KK + n];
    float r3 = fb[3 * KK + n];

    // previous-step state for the deferred argmax
    float4 pA, pB, pC, pD;
    float  pmax = 0.0f;

    auto step = [&](int t, float featval) {
        // ---- issue fv reads for step t (latency overlapped by deferred argmax) ----
        const float4* fp = (const float4*)&fv_lds[t & 1][pbase];
        const float4 fa = fp[0], fc = fp[1], fe = fp[2], fh = fp[3];

        // ---- deferred argmax + bp store for step t-1 (independent of reads) ----
        if (t > 0) {
            // local index (0..15) of first match, compile-time consts only
            const int s0  = (pA.x == pmax) ?  0 : 127;
            const int s1  = (pA.y == pmax) ?  1 : 127;
            const int s2  = (pA.z == pmax) ?  2 : 127;
            const int s3  = (pA.w == pmax) ?  3 : 127;
            const int s4  = (pB.x == pmax) ?  4 : 127;
            const int s5  = (pB.y == pmax) ?  5 : 127;
            const int s6  = (pB.z == pmax) ?  6 : 127;
            const int s7  = (pB.w == pmax) ?  7 : 127;
            const int s8  = (pC.x == pmax) ?  8 : 127;
            const int s9  = (pC.y == pmax) ?  9 : 127;
            const int s10 = (pC.z == pmax) ? 10 : 127;
            const int s11 = (pC.w == pmax) ? 11 : 127;
            const int s12 = (pD.x == pmax) ? 12 : 127;
            const int s13 = (pD.y == pmax) ? 13 : 127;
            const int s14 = (pD.z == pmax) ? 14 : 127;
            const int s15 = (pD.w == pmax) ? 15 : 127;
            int sl = min(min(min(min(s0, s1), min(s2, s3)),
                             min(min(s4, s5), min(s6, s7))),
                         min(min(min(s8, s9), min(s10, s11)),
                             min(min(s12, s13), min(s14, s15))));
            int idx = min(sl + pbase, 127);          // global p, 127 if no match here
            idx = min(idx, dpp_i<DPP_XOR1>(idx));
            idx = min(idx, dpp_i<DPP_XOR2>(idx));    // smallest matching p in row
            if (j == 0) bpb[(size_t)(t - 1) * KK + n] = (unsigned char)idx;
        }

        // ---- scores for this lane's 16 p's ----
        float4 vA, vB, vC, vD;
        vA.x = fa.x + tA.x; vA.y = fa.y + tA.y; vA.z = fa.z + tA.z; vA.w = fa.w + tA.w;
        vB.x = fc.x + tB.x; vB.y = fc.y + tB.y; vB.z = fc.z + tB.z; vB.w = fc.w + tB.w;
        vC.x = fe.x + tC.x; vC.y = fe.y + tC.y; vC.z = fe.z + tC.z; vC.w = fe.w + tC.w;
        vD.x = fh.x + tD.x; vD.y = fh.y + tD.y; vD.z = fh.z + tD.z; vD.w = fh.w + tD.w;

        // in-lane max (max3-friendly)
        const float mA = fmaxf(fmaxf(vA.x, vA.y), fmaxf(vA.z, vA.w));
        const float mB = fmaxf(fmaxf(vB.x, vB.y), fmaxf(vB.z, vB.w));
        const float mC = fmaxf(fmaxf(vC.x, vC.y), fmaxf(vC.z, vC.w));
        const float mD = fmaxf(fmaxf(vD.x, vD.y), fmaxf(vD.z, vD.w));
        float m = fmaxf(fmaxf(mA, mB), fmaxf(mC, mD));
        // cross-lane max over the 4 lanes of this row (quad DPP)
        m = fmaxf(m, dpp_f<DPP_XOR1>(m));
        m = fmaxf(m, dpp_f<DPP_XOR2>(m));

        if (j == 0) fv_lds[(t + 1) & 1][n] = m + featval;   // 16 consecutive dwords

        // save state for deferred argmax
        pA = vA; pB = vB; pC = vC; pD = vD; pmax = m;

        lds_barrier();
    };

    for (int t = 0; t < TT; t += 4) {
        float nr0 = fb[((t + 4 < TT) ? (t + 4) : (TT - 1)) * KK + n];
        step(t + 0, r0); r0 = nr0;
        float nr1 = fb[((t + 5 < TT) ? (t + 5) : (TT - 1)) * KK + n];
        step(t + 1, r1); r1 = nr1;
        float nr2 = fb[((t + 6 < TT) ? (t + 6) : (TT - 1)) * KK + n];
        step(t + 2, r2); r2 = nr2;
        float nr3 = fb[((t + 7 < TT) ? (t + 7) : (TT - 1)) * KK + n];
        step(t + 3, r3); r3 = nr3;
    }

    // ---- trailing argmax for t = TT-1 ----
    {
        const int s0  = (pA.x == pmax) ?  0 : 127;
        const int s1  = (pA.y == pmax) ?  1 : 127;
        const int s2  = (pA.z == pmax) ?  2 : 127;
        const int s3  = (pA.w == pmax) ?  3 : 127;
        const int s4  = (pB.x == pmax) ?  4 : 127;
        const int s5  = (pB.y == pmax) ?  5 : 127;
        const int s6  = (pB.z == pmax) ?  6 : 127;
        const int s7  = (pB.w == pmax) ?  7 : 127;
        const int s8  = (pC.x == pmax) ?  8 : 127;
        const int s9  = (pC.y == pmax) ?  9 : 127;
        const int s10 = (pC.z == pmax) ? 10 : 127;
        const int s11 = (pC.w == pmax) ? 11 : 127;
        const int s12 = (pD.x == pmax) ? 12 : 127;
        const int s13 = (pD.y == pmax) ? 13 : 127;
        const int s14 = (pD.z == pmax) ? 14 : 127;
        const int s15 = (pD.w == pmax) ? 15 : 127;
        int sl = min(min(min(min(s0, s1), min(s2, s3)),
                         min(min(s4, s5), min(s6, s7))),
                     min(min(min(s8, s9), min(s10, s11)),
                         min(min(s12, s13), min(s14, s15))));
        int idx = min(sl + pbase, 127);
        idx = min(idx, dpp_i<DPP_XOR1>(idx));
        idx = min(idx, dpp_i<DPP_XOR2>(idx));
        if (j == 0) bpb[(size_t)(TT - 1) * KK + n] = (unsigned char)idx;
    }

    __syncthreads();   // full drain: all bp stores visible block-wide

    // ---- chunk-map composition: wave w composes chunks 8w..8w+7 ----
    {
        const int c0 = w * 8;
        const unsigned char* q[8];
        int M[8], cur[8];
#pragma unroll
        for (int k = 0; k < 8; ++k) {
            q[k] = bpb + (size_t)(c0 + k) * CHUNK * KK + lane;
            M[k] = lane;
            cur[k] = q[k][0];
        }
        for (int t = 0; t < CHUNK; ++t) {
            int nxt[8];
#pragma unroll
            for (int k = 0; k < 8; ++k)
                nxt[k] = (t + 1 < CHUNK) ? (int)q[k][(t + 1) * KK] : 0;
#pragma unroll
            for (int k = 0; k < 8; ++k) {
                M[k] = __shfl(M[k], cur[k]);
                cur[k] = nxt[k];
            }
        }
#pragma unroll
        for (int k = 0; k < 8; ++k) cmap[c0 + k][lane] = M[k];
    }

    // ---- terminal argmax (wave 0, butterfly, first-max tie-break) ----
    if (w == 0) {
        float bv = fv_lds[TT & 1][lane] + tstop;   // TT even -> buffer 0
        int bi = lane;
#pragma unroll
        for (int off = 1; off < 64; off <<= 1) {
            const float ov = __shfl_xor(bv, off);
            const int   oi = __shfl_xor(bi, off);
            const bool take = (ov > bv) || (ov == bv && oi < bi);
            bv = take ? ov : bv;
            bi = take ? oi : bi;
        }
        if (lane == 0) { out[b] = bv; bl_lds = bi; }
    }
    __syncthreads();

    // ---- chunk-boundary tags via composed maps (serial, 32 LDS hops) ----
    if (tid == 0) {
        int x = bl_lds;
        be_lds[NCHUNK - 1] = x;
        for (int c = NCHUNK - 1; c >= 1; --c) {
            x = cmap[c][x];
            be_lds[c - 1] = x;
        }
    }
    __syncthreads();

    // ---- parallel interior backtrace (32 chunks, one lane each) ----
    if (tid < NCHUNK) {
        const int c = tid;
        int x = be_lds[c];
        float* po = out + BB + (size_t)b * TT;
        for (int t = (c + 1) * CHUNK - 1; t >= c * CHUNK; --t) {
            po[t] = (float)x;
            x = (int)bpb[(size_t)t * KK + x];
        }
    }
}

extern "C" void kernel_launch(void* const* d_in, const int* in_sizes, int n_in,
                              void* d_out, int out_size, void* d_ws, size_t ws_size,
                              hipStream_t stream) {
    const float* feats = (const float*)d_in[0];
    const float* trans = (const float*)d_in[1];
    const int* start_tag = (const int*)d_in[2];
    const int* stop_tag  = (const int*)d_in[3];
    float* out = (float*)d_out;
    unsigned char* bp = (unsigned char*)d_ws;   // B*T*K = 33.5 MB backpointers

    viterbi_fwd_bt<<<BB, 256, 0, stream>>>(feats, trans, start_tag, stop_tag, out, bp);
}

// Round 5
// 554.158 us; speedup vs baseline: 1.3953x; 1.3953x over previous
//
#include <hip/hip_runtime.h>
#include <stdint.h>

#define BB 256
#define TT 2048
#define KK 64
#define CHUNK 64
#define NCHUNK (TT / CHUNK)   // 32
#define WLEN 128
#define NWIN (TT / WLEN)      // 16
#define NEG_INF_F (-10000.0f)

// DPP cross-lane helpers (free VALU permutes within 16-lane rows)
#define DPP_XOR1 0xB1   // quad_perm [1,0,3,2]
#define DPP_XOR2 0x4E   // quad_perm [2,3,0,1]
#define DPP_HMIR 0x141  // row_half_mirror (== xor4 once quads reduced)

template <int CTRL>
__device__ __forceinline__ float dpp_f(float x) {
    return __int_as_float(__builtin_amdgcn_update_dpp(
        0, __float_as_int(x), CTRL, 0xF, 0xF, true));
}
template <int CTRL>
__device__ __forceinline__ int dpp_i(int x) {
    return __builtin_amdgcn_update_dpp(0, x, CTRL, 0xF, 0xF, true);
}

// LDS-only barrier: never drains vmcnt (bp stores / window loads stay in flight)
__device__ __forceinline__ void lds_barrier() {
    asm volatile("s_waitcnt lgkmcnt(0)\n\ts_barrier" ::: "memory");
}

__device__ __forceinline__ void gload_lds16(const void* g, void* l) {
    __builtin_amdgcn_global_load_lds(
        (const __attribute__((address_space(1))) void*)g,
        (__attribute__((address_space(3))) void*)l, 16, 0, 0);
}

__global__ __launch_bounds__(512, 2)
void viterbi_fwd_bt(const float* __restrict__ feats,
                    const float* __restrict__ trans,
                    const int* __restrict__ start_tag_p,
                    const int* __restrict__ stop_tag_p,
                    float* __restrict__ out,
                    unsigned char* __restrict__ bp_ws)
{
    const int b    = blockIdx.x;
    const int tid  = threadIdx.x;
    const int lane = tid & 63;
    const int w    = __builtin_amdgcn_readfirstlane(tid >> 6);  // wave 0..7
    const int g    = lane >> 3;        // row group within wave
    const int j    = lane & 7;         // p-chunk within row
    const int n    = w * 8 + g;        // owned output row
    const int pbase = j * 8;

    const int start_tag = *start_tag_p;
    const int stop_tag  = *stop_tag_p;

    __shared__ float fv_lds[2][KK];          // double-buffered Viterbi variables
    __shared__ float feat_lds[2][WLEN][KK];  // 64KB feat window double buffer
    __shared__ int   cmap[NCHUNK][KK];       // composed backpointer maps
    __shared__ int   be_lds[NCHUNK];
    __shared__ int   bl_lds;

    const float* fb = feats + (size_t)b * TT * KK;
    unsigned char* bpb = bp_ws + (size_t)b * TT * KK;

    // async window stage: wave w fills its 4KB slice, 4 x 1KB issues (linear)
    auto issue_win = [&](int widx, int bufsel) {
        const char* gsrc = (const char*)(fb + (size_t)widx * WLEN * KK)
                         + w * 4096 + lane * 16;
        char* ldst = (char*)&feat_lds[bufsel][0][0] + w * 4096;
#pragma unroll
        for (int k2 = 0; k2 < 4; ++k2)
            gload_lds16(gsrc + k2 * 1024, ldst + k2 * 1024);
    };
    issue_win(0, 0);   // window 0 in flight ASAP

    // per-lane transition fragment: trans[n][pbase .. pbase+7]
    const float4* trp = (const float4*)&trans[n * KK + pbase];
    const float4 tA = trp[0], tB = trp[1];
    const float tstop = trans[stop_tag * KK + lane];

    if (tid < KK) fv_lds[0][tid] = (tid == start_tag) ? 0.0f : NEG_INF_F;

    __syncthreads();   // drains vmcnt(0): window 0 complete + fv init visible
    issue_win(1, 1);   // window 1 in flight across window 0's 128 steps

    // previous-step state for the deferred argmax
    float4 pA = make_float4(0, 0, 0, 0), pB = make_float4(0, 0, 0, 0);
    float  pmax = 0.0f;

    auto step = [&](int t, const float* frow) {
        // issue LDS reads for step t (latency overlapped by deferred argmax)
        const float4* fp = (const float4*)&fv_lds[t & 1][pbase];
        const float4 fa = fp[0], fc = fp[1];
        const float featval = frow[n];     // 8-lane broadcast, conflict-free

        // deferred argmax + bp store for step t-1 (register-only inputs)
        if (t > 0) {
            const int s0 = (pA.x == pmax) ? 0 : 127;
            const int s1 = (pA.y == pmax) ? 1 : 127;
            const int s2 = (pA.z == pmax) ? 2 : 127;
            const int s3 = (pA.w == pmax) ? 3 : 127;
            const int s4 = (pB.x == pmax) ? 4 : 127;
            const int s5 = (pB.y == pmax) ? 5 : 127;
            const int s6 = (pB.z == pmax) ? 6 : 127;
            const int s7 = (pB.w == pmax) ? 7 : 127;
            const int m1 = min(min(s0, s1), s2);   // v_min3
            const int m2 = min(min(s3, s4), s5);
            const int m3 = min(s6, s7);
            int idx = min(min(min(m1, m2), m3) + pbase, 127);
            idx = min(idx, dpp_i<DPP_XOR1>(idx));
            idx = min(idx, dpp_i<DPP_XOR2>(idx));
            idx = min(idx, dpp_i<DPP_HMIR>(idx));  // smallest matching p
            if (j == 0) bpb[(size_t)(t - 1) * KK + n] = (unsigned char)idx;
        }

        // scores for this lane's 8 p's
        float4 vA, vB;
        vA.x = fa.x + tA.x; vA.y = fa.y + tA.y;
        vA.z = fa.z + tA.z; vA.w = fa.w + tA.w;
        vB.x = fc.x + tB.x; vB.y = fc.y + tB.y;
        vB.z = fc.z + tB.z; vB.w = fc.w + tB.w;

        // in-lane max (v_max3-friendly)
        const float ma = fmaxf(fmaxf(vA.x, vA.y), vA.z);
        const float mb = fmaxf(fmaxf(vA.w, vB.x), vB.y);
        const float mc = fmaxf(vB.z, vB.w);
        float m = fmaxf(fmaxf(ma, mb), mc);
        // cross-lane max over the 8 lanes of this row (free DPP)
        m = fmaxf(m, dpp_f<DPP_XOR1>(m));
        m = fmaxf(m, dpp_f<DPP_XOR2>(m));
        m = fmaxf(m, dpp_f<DPP_HMIR>(m));

        if (j == 0) fv_lds[(t + 1) & 1][n] = m + featval;

        pA = vA; pB = vB; pmax = m;
        lds_barrier();
    };

    for (int W = 0; W < NWIN; ++W) {
        const float (*fw)[KK] = feat_lds[W & 1];
        const int base = W * WLEN;
        for (int tt = 0; tt < WLEN; tt += 4) {
            step(base + tt + 0, fw[tt + 0]);
            step(base + tt + 1, fw[tt + 1]);
            step(base + tt + 2, fw[tt + 2]);
            step(base + tt + 3, fw[tt + 3]);
        }
        // boundary: ensure window W+1 (issued one window ago) is resident
        asm volatile("s_waitcnt vmcnt(0)" ::: "memory");
        __builtin_amdgcn_s_barrier();
        if (W + 2 < NWIN) issue_win(W + 2, W & 1);   // overwrite just-read buffer
    }

    // trailing argmax for t = TT-1
    {
        const int s0 = (pA.x == pmax) ? 0 : 127;
        const int s1 = (pA.y == pmax) ? 1 : 127;
        const int s2 = (pA.z == pmax) ? 2 : 127;
        const int s3 = (pA.w == pmax) ? 3 : 127;
        const int s4 = (pB.x == pmax) ? 4 : 127;
        const int s5 = (pB.y == pmax) ? 5 : 127;
        const int s6 = (pB.z == pmax) ? 6 : 127;
        const int s7 = (pB.w == pmax) ? 7 : 127;
        const int m1 = min(min(s0, s1), s2);
        const int m2 = min(min(s3, s4), s5);
        const int m3 = min(s6, s7);
        int idx = min(min(min(m1, m2), m3) + pbase, 127);
        idx = min(idx, dpp_i<DPP_XOR1>(idx));
        idx = min(idx, dpp_i<DPP_XOR2>(idx));
        idx = min(idx, dpp_i<DPP_HMIR>(idx));
        if (j == 0) bpb[(size_t)(TT - 1) * KK + n] = (unsigned char)idx;
    }

    __syncthreads();   // full drain: all bp stores visible block-wide

    // ---- chunk-map composition: wave w composes chunks 4w..4w+3 ----
    {
        const int c0 = w * 4;
        const unsigned char* q0 = bpb + (size_t)(c0 + 0) * CHUNK * KK + lane;
        const unsigned char* q1 = bpb + (size_t)(c0 + 1) * CHUNK * KK + lane;
        const unsigned char* q2 = bpb + (size_t)(c0 + 2) * CHUNK * KK + lane;
        const unsigned char* q3 = bpb + (size_t)(c0 + 3) * CHUNK * KK + lane;
        int M0 = lane, M1 = lane, M2 = lane, M3 = lane;
        int a0 = q0[0], a1 = q1[0], a2 = q2[0], a3 = q3[0];
        int b0 = q0[KK], b1 = q1[KK], b2 = q2[KK], b3 = q3[KK];
        for (int t = 0; t < CHUNK; t += 2) {
            int n0 = 0, n1 = 0, n2 = 0, n3 = 0, m0 = 0, m1 = 0, m2 = 0, m3 = 0;
            if (t + 2 < CHUNK) {
                n0 = q0[(t + 2) * KK]; n1 = q1[(t + 2) * KK];
                n2 = q2[(t + 2) * KK]; n3 = q3[(t + 2) * KK];
                m0 = q0[(t + 3) * KK]; m1 = q1[(t + 3) * KK];
                m2 = q2[(t + 3) * KK]; m3 = q3[(t + 3) * KK];
            }
            M0 = __shfl(M0, a0); M1 = __shfl(M1, a1);
            M2 = __shfl(M2, a2); M3 = __shfl(M3, a3);
            M0 = __shfl(M0, b0); M1 = __shfl(M1, b1);
            M2 = __shfl(M2, b2); M3 = __shfl(M3, b3);
            a0 = n0; a1 = n1; a2 = n2; a3 = n3;
            b0 = m0; b1 = m1; b2 = m2; b3 = m3;
        }
        cmap[c0 + 0][lane] = M0; cmap[c0 + 1][lane] = M1;
        cmap[c0 + 2][lane] = M2; cmap[c0 + 3][lane] = M3;
    }

    // ---- terminal argmax (wave 0, butterfly, first-max tie-break) ----
    if (w == 0) {
        float bv = fv_lds[TT & 1][lane] + tstop;   // TT even -> buffer 0
        int bi = lane;
#pragma unroll
        for (int off = 1; off < 64; off <<= 1) {
            const float ov = __shfl_xor(bv, off);
            const int   oi = __shfl_xor(bi, off);
            const bool take = (ov > bv) || (ov == bv && oi < bi);
            bv = take ? ov : bv;
            bi = take ? oi : bi;
        }
        if (lane == 0) { out[b] = bv; bl_lds = bi; }
    }
    __syncthreads();

    // ---- chunk-boundary tags via composed maps (serial, 32 LDS hops) ----
    if (tid == 0) {
        int x = bl_lds;
        be_lds[NCHUNK - 1] = x;
        for (int c = NCHUNK - 1; c >= 1; --c) {
            x = cmap[c][x];
            be_lds[c - 1] = x;
        }
    }
    __syncthreads();

    // ---- parallel interior backtrace (32 chunks, one lane each) ----
    if (tid < NCHUNK) {
        const int c = tid;
        int x = be_lds[c];
        float* po = out + BB + (size_t)b * TT;
        for (int t = (c + 1) * CHUNK - 1; t >= c * CHUNK; --t) {
            po[t] = (float)x;
            x = (int)bpb[(size_t)t * KK + x];
        }
    }
}

extern "C" void kernel_launch(void* const* d_in, const int* in_sizes, int n_in,
                              void* d_out, int out_size, void* d_ws, size_t ws_size,
                              hipStream_t stream) {
    const float* feats = (const float*)d_in[0];
    const float* trans = (const float*)d_in[1];
    const int* start_tag = (const int*)d_in[2];
    const int* stop_tag  = (const int*)d_in[3];
    float* out = (float*)d_out;
    unsigned char* bp = (unsigned char*)d_ws;   // B*T*K = 33.5 MB backpointers

    viterbi_fwd_bt<<<BB, 512, 0, stream>>>(feats, trans, start_tag, stop_tag, out, bp);
}